// Round 8
// baseline (140.473 us; speedup 1.0000x reference)
//
#include <hip/hip_runtime.h>
#include <hip/hip_bf16.h>

#define BB 64
#define PP 576
#define DD 1024
#define HH 512

typedef __attribute__((ext_vector_type(4))) float f32x4;
typedef __attribute__((ext_vector_type(8))) short bf16x8;

__device__ __forceinline__ unsigned short f2bf(float f) {
    union { float f; unsigned u; } v; v.f = f;
    unsigned r = v.u + 0x7FFF + ((v.u >> 16) & 1);
    return (unsigned short)(r >> 16);
}

__device__ __forceinline__ float fast_tanh(float x) {
    float e = __expf(2.f * x);
    return 1.f - 2.f / (e + 1.f);
}

__device__ __forceinline__ void gload16(const void* g, void* l) {
    __builtin_amdgcn_global_load_lds((const __attribute__((address_space(1))) unsigned int*)g,
                                     (__attribute__((address_space(3))) unsigned int*)l,
                                     16, 0, 0);
}

// pack 8 f32 -> bf16x8 via HW packed convert (RNE)
__device__ __forceinline__ bf16x8 cvt8(f32x4 a, f32x4 b) {
    union { bf16x8 v; unsigned u[4]; } r;
    asm("v_cvt_pk_bf16_f32 %0, %1, %2" : "=v"(r.u[0]) : "v"(a.x), "v"(a.y));
    asm("v_cvt_pk_bf16_f32 %0, %1, %2" : "=v"(r.u[1]) : "v"(a.z), "v"(a.w));
    asm("v_cvt_pk_bf16_f32 %0, %1, %2" : "=v"(r.u[2]) : "v"(b.x), "v"(b.y));
    asm("v_cvt_pk_bf16_f32 %0, %1, %2" : "=v"(r.u[3]) : "v"(b.z), "v"(b.w));
    return r.v;
}

#define VMW(n)  asm volatile("s_waitcnt vmcnt(" #n ")" ::: "memory")
#define BARRIER asm volatile("s_waitcnt lgkmcnt(0)\n\ts_barrier" ::: "memory")

// ---- kernel 0: convert W_img fp32 -> bf16 in ws ----
__global__ __launch_bounds__(256) void k_convert(const float* __restrict__ w,
                                                 unsigned short* __restrict__ o) {
    int i = (blockIdx.x * 256 + threadIdx.x) * 4;
    f32x4 v = *(const f32x4*)(w + i);
    ushort4 r;
    r.x = f2bf(v.x); r.y = f2bf(v.y); r.z = f2bf(v.z); r.w = f2bf(v.w);
    *(ushort4*)(o + i) = r;
}

// ---- kernel 1: g[b][h] = tanh(seq[b]·W_seq[h]) * W_w[h]  (fp32 exact path) ----
__global__ __launch_bounds__(128) void k_seq(const float* __restrict__ seq,
                                             const float* __restrict__ W_seq,
                                             const float* __restrict__ W_w,
                                             float* __restrict__ g) {
    int b = blockIdx.x;
    int h = blockIdx.y * 128 + threadIdx.x;
    __shared__ float s_seq[DD];
    #pragma unroll
    for (int i = 0; i < 8; i++) s_seq[threadIdx.x + i * 128] = seq[b * DD + threadIdx.x + i * 128];
    __syncthreads();
    const float* wr = W_seq + (size_t)h * DD;
    float acc = 0.f;
    #pragma unroll 4
    for (int d = 0; d < DD; d += 4) {
        f32x4 w4 = *(const f32x4*)(wr + d);
        acc += w4.x * s_seq[d] + w4.y * s_seq[d + 1] + w4.z * s_seq[d + 2] + w4.w * s_seq[d + 3];
    }
    g[b * HH + h] = fast_tanh(acc) * W_w[h];
}

// ---- kernel 2: partial scores — deep-slack pipeline, one non-draining barrier/round ----
// Block 256 thr = 4 waves. Tile BM=64 x HC=256, BK=32, 32 rounds. LDS 40 KB (4 blk/CU).
// A: 2-reg-slot ring at issue distance 3 (slot freed by ds_write one round before
//    its next landing). A(t+1) waited at round t was issued at round t-2 (~2-round slack
//    vs ~900cy HBM). B: wave-private gload_lds, issued t-1 for t+... (1-round slack vs
//    L2-hot Wb). vmcnt counts depend only on per-round group sizes (2A+4B=6), which the
//    asm memory-clobbers partition -> robust to intra-group scheduling.
// Round: compute(t) | VMW(6)=A(t+1) | cvt_pk+ds_write As(t+1) | lgkm0+s_barrier |
//        issue B(t+2),A(t+3) | VMW(8)=B(t+1).  vmcnt never 0 in steady state.
__global__ __launch_bounds__(256) void k_scores(const float* __restrict__ img,
                                                const unsigned short* __restrict__ Wb,
                                                const float* __restrict__ g,
                                                float* __restrict__ sp) {
    // bijective XCD swizzle (1152 = 8 * 144): ch-pairs of one (rt,b) land on same XCD
    int orig = blockIdx.x + 18 * blockIdx.y;
    int logical = (orig & 7) * 144 + (orig >> 3);
    int ch = logical & 1;
    int rt = (logical >> 1) % 9;
    int b  = logical / 18;
    int p0 = rt * 64;
    int h0 = ch * 256;
    int tid = threadIdx.x;
    int w = tid >> 6, lane = tid & 63;
    int r15 = lane & 15;
    int kq = lane >> 4;
    int csw = kq ^ ((r15 >> 1) & 3);          // swizzled 16B-chunk for ds_read

    __shared__ unsigned short As[2][64 * 32];    // 2 x 4 KB
    __shared__ unsigned short Bs[2][256 * 32];   // 2 x 16 KB -> 40960 B total

    float gr[4];
    #pragma unroll
    for (int n = 0; n < 4; ++n) gr[n] = g[b * HH + h0 + w * 64 + n * 16 + r15];
    VMW(0);   // drain gr loads so pipeline vmcnt counts stay exact

    f32x4 acc[4][4];
    #pragma unroll
    for (int m = 0; m < 4; m++)
        #pragma unroll
        for (int n = 0; n < 4; n++) acc[m][n] = (f32x4)0.f;

    // A staging: thread t -> row t>>2, 8 f32 at col (t&3)*8; swizzled ds_write
    int ar = tid >> 2, ac = tid & 3;
    const float* asrc = img + ((size_t)(b * PP + p0 + ar)) * DD + ac * 8;
    int aw = ar * 32 + ((ac ^ ((ar >> 1) & 3)) * 8);

    // B staging: wave w covers rows [w*64,(w+1)*64); issue i: rows w*64+i*16+(lane>>2)
    int rl = lane >> 2;
    int bswz = (lane & 3) ^ ((rl >> 1) & 3);  // pre-swizzled global chunk
    const unsigned short* bbase = Wb + (size_t)h0 * DD;

    f32x4 uaS0[2], uaS1[2];   // A register ring, 2 static slots

    auto ISSUEA = [&](f32x4 (&ua)[2], int t) {
        const float* s = asrc + t * 32;
        ua[0] = *(const f32x4*)s;
        ua[1] = *(const f32x4*)(s + 4);
    };
    auto ISSUEB = [&](unsigned short* dB, int t) {
        int k0 = t * 32;
        #pragma unroll
        for (int i = 0; i < 4; ++i) {
            int hr = w * 64 + i * 16 + rl;
            gload16(bbase + (size_t)hr * DD + k0 + bswz * 8, dB + (w * 64 + i * 16) * 32);
        }
    };
    auto PACK = [&](const f32x4 (&ua)[2], unsigned short* dA) {
        *(bf16x8*)&dA[aw] = cvt8(ua[0], ua[1]);
    };
    auto COMPUTE = [&](const unsigned short* cA, const unsigned short* cB) {
        bf16x8 af[4], bf[4];
        #pragma unroll
        for (int m = 0; m < 4; ++m)
            af[m] = *(const bf16x8*)&cA[(m * 16 + r15) * 32 + csw * 8];
        #pragma unroll
        for (int n = 0; n < 4; ++n)
            bf[n] = *(const bf16x8*)&cB[(w * 64 + n * 16 + r15) * 32 + csw * 8];
        #pragma unroll
        for (int m = 0; m < 4; ++m)
            #pragma unroll
            for (int n = 0; n < 4; ++n)
                acc[m][n] = __builtin_amdgcn_mfma_f32_16x16x32_bf16(af[m], bf[n], acc[m][n], 0, 0, 0);
    };

    // ---- prologue: establish steady-state invariant at t=0 entry ----
    ISSUEA(uaS0, 0); ISSUEA(uaS1, 1); ISSUEB(&Bs[0][0], 0);   // 8 ops
    VMW(6);                      // A(0) landed (youngest 6 = A1+B0)
    PACK(uaS0, &As[0][0]);
    ISSUEB(&Bs[1][0], 1); ISSUEA(uaS0, 2);                    // +6 ops
    BARRIER;                     // As(0) visible; B gloads stay in flight
    VMW(6);                      // B(0) landed (youngest 6 = B1+A2)

    // ---- main loop: rounds t=0..27 ----
    for (int i = 0; i < 14; ++i) {
        int t = 2 * i;
        // even round: c=0, s=1
        COMPUTE(&As[0][0], &Bs[0][0]);
        VMW(6);                               // A(t+1) landed
        PACK(uaS1, &As[1][0]);
        BARRIER;
        ISSUEB(&Bs[0][0], t + 2); ISSUEA(uaS1, t + 3);
        VMW(8);                               // B(t+1) landed
        // odd round: c=1, s=0
        COMPUTE(&As[1][0], &Bs[1][0]);
        VMW(6);                               // A(t+2) landed
        PACK(uaS0, &As[0][0]);
        BARRIER;
        ISSUEB(&Bs[1][0], t + 3); ISSUEA(uaS0, t + 4);
        VMW(8);                               // B(t+2) landed
    }
    // ---- tail: t=28..31 ----
    COMPUTE(&As[0][0], &Bs[0][0]);   // t=28
    VMW(6); PACK(uaS1, &As[1][0]); BARRIER;
    ISSUEB(&Bs[0][0], 30); ISSUEA(uaS1, 31);
    VMW(8);
    COMPUTE(&As[1][0], &Bs[1][0]);   // t=29
    VMW(6); PACK(uaS0, &As[0][0]); BARRIER;
    ISSUEB(&Bs[1][0], 31);
    VMW(6);
    COMPUTE(&As[0][0], &Bs[0][0]);   // t=30
    VMW(4); PACK(uaS1, &As[1][0]); BARRIER;
    VMW(0);
    COMPUTE(&As[1][0], &Bs[1][0]);   // t=31

    // ---- epilogue: tanh * g, reduce over this block's 256 cols ----
    float part[4][4];
    #pragma unroll
    for (int m = 0; m < 4; m++)
        #pragma unroll
        for (int j = 0; j < 4; j++) part[m][j] = 0.f;
    #pragma unroll
    for (int m = 0; m < 4; ++m)
        #pragma unroll
        for (int n = 0; n < 4; ++n) {
            float gv = gr[n];
            f32x4 v = acc[m][n];
            #pragma unroll
            for (int j = 0; j < 4; ++j) part[m][j] += fast_tanh(v[j]) * gv;
        }
    #pragma unroll
    for (int mask = 1; mask < 16; mask <<= 1)
        #pragma unroll
        for (int m = 0; m < 4; ++m)
            #pragma unroll
            for (int j = 0; j < 4; ++j)
                part[m][j] += __shfl_xor(part[m][j], mask, 64);

    __syncthreads();                 // all waves done with As/Bs
    float* red = (float*)&As[0][0];
    if (r15 == 0) {
        int hi = lane >> 4;
        #pragma unroll
        for (int m = 0; m < 4; ++m)
            #pragma unroll
            for (int j = 0; j < 4; ++j)
                red[w * 64 + m * 16 + hi * 4 + j] = part[m][j];
    }
    __syncthreads();
    if (tid < 64) {
        float s = red[tid] + red[64 + tid] + red[128 + tid] + red[192 + tid];
        sp[(size_t)ch * (BB * PP) + b * PP + p0 + tid] = s;
    }
}

// ---- kernel 3: sum the 2 col-half partials + softmax over P per batch ----
__global__ __launch_bounds__(576) void k_softmax(const float* __restrict__ sp,
                                                 float* __restrict__ alpha) {
    int b = blockIdx.x;
    int t = threadIdx.x;  // 0..575
    __shared__ float red[9];
    float s = sp[b * PP + t] + sp[BB * PP + b * PP + t];
    float m = s;
    #pragma unroll
    for (int off = 32; off; off >>= 1) m = fmaxf(m, __shfl_xor(m, off, 64));
    int w = t >> 6;
    if ((t & 63) == 0) red[w] = m;
    __syncthreads();
    float gm = red[0];
    #pragma unroll
    for (int i = 1; i < 9; i++) gm = fmaxf(gm, red[i]);
    float e = __expf(s - gm);
    float sum = e;
    #pragma unroll
    for (int off = 32; off; off >>= 1) sum += __shfl_xor(sum, off, 64);
    __syncthreads();
    if ((t & 63) == 0) red[w] = sum;
    __syncthreads();
    float gsum = 0.f;
    #pragma unroll
    for (int i = 0; i < 9; i++) gsum += red[i];
    alpha[b * PP + t] = e / gsum;
}

// ---- kernel 4: partial weighted sums over 64-patch chunks ----
__global__ __launch_bounds__(256) void k_attend(const float* __restrict__ img,
                                                const float* __restrict__ alpha,
                                                float* __restrict__ part) {
    int b = blockIdx.y;
    int pc = blockIdx.x;  // 0..8
    int t = threadIdx.x;
    __shared__ float al[64];
    if (t < 64) al[t] = alpha[b * PP + pc * 64 + t];
    __syncthreads();
    int d = t * 4;
    f32x4 acc = (f32x4)0.f;
    const float* base = img + ((size_t)b * PP + (size_t)pc * 64) * DD + d;
    #pragma unroll 4
    for (int i = 0; i < 64; i++) {
        f32x4 v = *(const f32x4*)(base + (size_t)i * DD);
        acc += al[i] * v;
    }
    float* o = part + ((size_t)pc * BB + b) * DD + d;
    *(f32x4*)o = acc;
}

// ---- kernel 5: reduce the 9 partials ----
__global__ __launch_bounds__(256) void k_reduce(const float* __restrict__ part,
                                                float* __restrict__ out) {
    int i = blockIdx.x * 256 + threadIdx.x;  // 0..65535
    float s = 0.f;
    #pragma unroll
    for (int pc = 0; pc < 9; pc++) s += part[pc * (BB * DD) + i];
    out[i] = s;
}

extern "C" void kernel_launch(void* const* d_in, const int* in_sizes, int n_in,
                              void* d_out, int out_size, void* d_ws, size_t ws_size,
                              hipStream_t stream) {
    const float* seq   = (const float*)d_in[0];   // [64,1024]
    const float* img   = (const float*)d_in[1];   // [64,576,1024]
    const float* W_seq = (const float*)d_in[2];   // [512,1024]
    const float* W_img = (const float*)d_in[3];   // [512,1024]
    const float* W_w   = (const float*)d_in[4];   // [1,512]
    float* out = (float*)d_out;                   // [64,1024]

    char* ws = (char*)d_ws;
    unsigned short* Wb = (unsigned short*)ws;                        // 1 MB
    float* g      = (float*)(ws + 1048576);                          // 128 KB
    float* sp     = (float*)(ws + 1048576 + 131072);                 // 2*144 KB (partial scores)
    float* alpha  = (float*)(ws + 1048576 + 131072 + 294912);        // 144 KB
    float* part   = (float*)(ws + 1048576 + 131072 + 294912 + 147456); // 2.25 MB

    k_convert<<<512, 256, 0, stream>>>(W_img, Wb);
    k_seq<<<dim3(BB, 4), 128, 0, stream>>>(seq, W_seq, W_w, g);
    k_scores<<<dim3(18, BB), 256, 0, stream>>>(img, Wb, g, sp);
    k_softmax<<<BB, 576, 0, stream>>>(sp, alpha);
    k_attend<<<dim3(9, BB), 256, 0, stream>>>(img, alpha, part);
    k_reduce<<<256, 256, 0, stream>>>(part, out);
}